// Round 9
// baseline (561.454 us; speedup 1.0000x reference)
//
#include <hip/hip_runtime.h>
#include <hip/hip_bf16.h>

// Problem constants
#define BB     2
#define SEQ    256
#define HH     2048
#define HKc    16
#define HVc    32
#define DKc    128
#define DVc    128
#define KC     4
#define KEYD   2048      // HKc*DKc
#define VALD   4096      // HVc*DVc
#define CONVD  8192      // 2*KEYD + VALD
#define MM     (BB*SEQ)  // 512
#define EPSf   1e-6f

typedef __attribute__((ext_vector_type(8))) short short8;
typedef __attribute__((ext_vector_type(4))) short short4v;
typedef __attribute__((ext_vector_type(4))) float floatx4;

__device__ __forceinline__ short f2bf(float f) {
  union { float f; unsigned u; } v; v.f = f;
  unsigned r = v.u + 0x7fffu + ((v.u >> 16) & 1u);   // RNE
  return (short)(r >> 16);
}

// -------- zero-fill (float4 per thread) -------------------------------------
__global__ __launch_bounds__(256) void zerof_kernel(float* __restrict__ p) {
  float4 z; z.x = 0.f; z.y = 0.f; z.z = 0.f; z.w = 0.f;
  *(float4*)&p[(size_t)(blockIdx.x * 256 + threadIdx.x) * 4] = z;
}

// -------- transpose-convert: W[K][N] fp32 -> Wt[N][K] bf16 ------------------
// 64k x 32n tile; writes are 32 FULL 128B lines per block.
__global__ __launch_bounds__(256) void trconv_kernel(
    const float* __restrict__ W, short* __restrict__ Wt, int K, int N) {
  __shared__ float ls[64][33];
  const int n0 = blockIdx.x * 32;
  const int k0 = blockIdx.y * 64;
  const int t = threadIdx.x;
#pragma unroll
  for (int it = 0; it < 2; ++it) {
    const int kr = (t >> 3) + it * 32;
    const int c4 = (t & 7) * 4;
    const float4 f = *(const float4*)&W[(size_t)(k0 + kr) * N + n0 + c4];
    ls[kr][c4] = f.x; ls[kr][c4 + 1] = f.y; ls[kr][c4 + 2] = f.z; ls[kr][c4 + 3] = f.w;
  }
  __syncthreads();
  const int r = t >> 3;           // 0..31 n-row
  const int kc = (t & 7) * 8;     // 0..56 k-chunk
  short8 s;
#pragma unroll
  for (int j = 0; j < 8; ++j) s[j] = f2bf(ls[kc + j][r]);
  *(short8*)&Wt[(size_t)(n0 + r) * K + k0 + kc] = s;
}

// -------- elementwise fp32 -> bf16 (8 per thread) ---------------------------
__global__ __launch_bounds__(256) void f2bf_kernel(
    const float* __restrict__ in, short* __restrict__ out) {
  const int i = blockIdx.x * 256 + threadIdx.x;
  const float4 a = *(const float4*)&in[(size_t)i * 8];
  const float4 b = *(const float4*)&in[(size_t)i * 8 + 4];
  short8 s;
  s[0] = f2bf(a.x); s[1] = f2bf(a.y); s[2] = f2bf(a.z); s[3] = f2bf(a.w);
  s[4] = f2bf(b.x); s[5] = f2bf(b.y); s[6] = f2bf(b.z); s[7] = f2bf(b.w);
  *(short8*)&out[(size_t)i * 8] = s;
}

// ---------- MFMA bf16 GEMM: C[M,N] (+)= A[M,K](bf16,lda) * Bt[N,K]^T --------
// Block tile 64m x 128n, BK=64 (v12: halves barrier count per K vs BK=32;
// 16 MFMA per barrier-pair), 256 threads = 4 waves (2x2), wave = 32m x 64n.
// Register prefetch of next K-step during MFMA. Split-K via blockIdx.z
// (atom=1 -> atomicAdd into pre-zeroed C).
#define PAD2 72   // shorts per LDS row: 64 data + 8 pad (144 B, 16B-aligned)
__global__ __launch_bounds__(256) void gemm_bf16(
    const short* __restrict__ A, const short* __restrict__ Bt,
    float* __restrict__ C, int M, int N, int Kd, int lda, int klen, int atom) {
  __shared__ short As[64 * PAD2];    // 9216 B
  __shared__ short Bs[128 * PAD2];   // 18432 B
  const int tid = threadIdx.x;
  const int wave = tid >> 6, lane = tid & 63;
  const int wm = (wave >> 1) * 32, wn = (wave & 1) * 64;
  const int bm = blockIdx.y * 64, bn = blockIdx.x * 128;
  const int koff = blockIdx.z * klen;
  floatx4 acc[2][4] = {};
  const int sr = tid >> 3;            // 0..31 row base
  const int skc = (tid & 7) * 8;      // 0..56 k-chunk (8 shorts)
  const int fm = lane & 15, fq = (lane >> 4) * 8;
  const short* Ap = A  + koff + skc;
  const short* Bp = Bt + koff + skc;
  short8 pa[2], pb[4];
#pragma unroll
  for (int it = 0; it < 2; ++it)
    pa[it] = *(const short8*)(Ap + (size_t)(bm + sr + it * 32) * lda);
#pragma unroll
  for (int it = 0; it < 4; ++it)
    pb[it] = *(const short8*)(Bp + (size_t)(bn + sr + it * 32) * Kd);
  for (int k0 = 0; k0 < klen; k0 += 64) {
#pragma unroll
    for (int it = 0; it < 2; ++it)
      *(short8*)&As[(sr + it * 32) * PAD2 + skc] = pa[it];
#pragma unroll
    for (int it = 0; it < 4; ++it)
      *(short8*)&Bs[(sr + it * 32) * PAD2 + skc] = pb[it];
    __syncthreads();
    if (k0 + 64 < klen) {
#pragma unroll
      for (int it = 0; it < 2; ++it)
        pa[it] = *(const short8*)(Ap + (size_t)(bm + sr + it * 32) * lda + k0 + 64);
#pragma unroll
      for (int it = 0; it < 4; ++it)
        pb[it] = *(const short8*)(Bp + (size_t)(bn + sr + it * 32) * Kd + k0 + 64);
    }
    short8 af[2][2], bfr[2][4];
#pragma unroll
    for (int hh = 0; hh < 2; ++hh) {
#pragma unroll
      for (int i = 0; i < 2; ++i)
        af[hh][i] = *(const short8*)&As[(wm + i * 16 + fm) * PAD2 + hh * 32 + fq];
#pragma unroll
      for (int j = 0; j < 4; ++j)
        bfr[hh][j] = *(const short8*)&Bs[(wn + j * 16 + fm) * PAD2 + hh * 32 + fq];
    }
#pragma unroll
    for (int hh = 0; hh < 2; ++hh)
#pragma unroll
      for (int i = 0; i < 2; ++i)
#pragma unroll
        for (int j = 0; j < 4; ++j)
          acc[i][j] = __builtin_amdgcn_mfma_f32_16x16x32_bf16(af[hh][i], bfr[hh][j], acc[i][j], 0, 0, 0);
    __syncthreads();
  }
  const int cn = lane & 15, cr0 = (lane >> 4) * 4;
  if (atom) {
#pragma unroll
    for (int i = 0; i < 2; ++i)
#pragma unroll
      for (int j = 0; j < 4; ++j)
#pragma unroll
        for (int r = 0; r < 4; ++r)
          atomicAdd(&C[(size_t)(bm + wm + i * 16 + cr0 + r) * N + bn + wn + j * 16 + cn],
                    acc[i][j][r]);
  } else {
#pragma unroll
    for (int i = 0; i < 2; ++i)
#pragma unroll
      for (int j = 0; j < 4; ++j)
#pragma unroll
        for (int r = 0; r < 4; ++r)
          C[(size_t)(bm + wm + i * 16 + cr0 + r) * N + bn + wn + j * 16 + cn] = acc[i][j][r];
  }
}

// -------- b/a projections fused with gating --------
__global__ __launch_bounds__(256) void proj_ab_kernel(
    const float* __restrict__ hs, const float* __restrict__ Wb,
    const float* __restrict__ Wa, const float* __restrict__ A_log,
    const float* __restrict__ dt_bias, float* __restrict__ g_out,
    float* __restrict__ beta_out) {
  __shared__ float xs[HH];
  __shared__ float part[4][64];
  const int row = blockIdx.x;
  const int t = threadIdx.x;
  for (int i = t; i < HH; i += 256) xs[i] = hs[(size_t)row * HH + i];
  __syncthreads();
  const int j = t & 63;
  const int kc = t >> 6;
  const float* W = (j < 32) ? Wb : Wa;
  const int jj = j & 31;
  float p = 0.f;
  const int k0 = kc * 512;
#pragma unroll 8
  for (int k = k0; k < k0 + 512; ++k) p += xs[k] * W[k * 32 + jj];
  part[kc][j] = p;
  __syncthreads();
  if (t < 64) {
    float dot = part[0][t] + part[1][t] + part[2][t] + part[3][t];
    if (t < 32) {
      beta_out[row * HVc + t] = 1.f / (1.f + expf(-dot));
    } else {
      int h = t - 32;
      float x = dot + dt_bias[h];
      float sp = (x > 20.f) ? x : log1pf(expf(x));
      g_out[row * HVc + h] = -expf(A_log[h]) * sp;
    }
  }
}

// -------- depthwise causal conv (K=4) + SiLU, parallel over s-chunks --------
#define CCH 16
__global__ __launch_bounds__(256) void conv_par_kernel(
    const float* __restrict__ mixed, const float* __restrict__ conv_state,
    const float* __restrict__ conv_w, const float* __restrict__ conv_b,
    float* __restrict__ cs) {
  const int c = blockIdx.x * 256 + threadIdx.x;   // channel
  const int s0 = blockIdx.y * CCH;
  const int b = blockIdx.z;
  const float4 w4 = *(const float4*)&conv_w[c * KC];
  const float bias = conv_b[c];
  float r0, r1, r2;
  if (s0 == 0) {
    size_t sb = (size_t)(b * CONVD + c) * (KC - 1);
    r0 = conv_state[sb + 0]; r1 = conv_state[sb + 1]; r2 = conv_state[sb + 2];
  } else {
    r0 = mixed[((size_t)(b * SEQ + s0 - 3)) * CONVD + c];
    r1 = mixed[((size_t)(b * SEQ + s0 - 2)) * CONVD + c];
    r2 = mixed[((size_t)(b * SEQ + s0 - 1)) * CONVD + c];
  }
#pragma unroll
  for (int s = s0; s < s0 + CCH; ++s) {
    size_t off = ((size_t)(b * SEQ + s)) * CONVD + c;
    float x = mixed[off];
    float acc = bias + r0 * w4.x + r1 * w4.y + r2 * w4.z + x * w4.w;
    cs[off] = acc / (1.f + expf(-acc));
    r0 = r1; r1 = r2; r2 = x;
  }
}

// -------- conv_state_out: last K-1 raw rows of mixed, [B,C,K-1] fp32 --------
__global__ __launch_bounds__(256) void conv_state_out_kernel(
    const float* __restrict__ mixed, float* __restrict__ out2) {
  int idx = blockIdx.x * 256 + threadIdx.x;  // over BB*CONVD*(KC-1)
  int t = idx % (KC - 1);
  int c = (idx / (KC - 1)) & (CONVD - 1);
  int b = idx / ((KC - 1) * CONVD);
  out2[idx] = mixed[((size_t)(b * SEQ + SEQ - (KC - 1) + t)) * CONVD + c];
}

// -------- per-head l2norm of q (scaled by DK^-0.5) and k, IN PLACE on cs ----
__global__ __launch_bounds__(64) void l2norm_kernel(float* __restrict__ cs) {
  int bx = blockIdx.x;          // row*32 + head*2 + which
  int which = bx & 1;
  int head = (bx >> 1) & 15;
  int row = bx >> 5;
  int lane = threadIdx.x;
  size_t base = (size_t)row * CONVD + (size_t)which * KEYD + head * DKc;
  float v0 = cs[base + lane];
  float v1 = cs[base + lane + 64];
  float ss = v0 * v0 + v1 * v1;
#pragma unroll
  for (int m = 1; m < 64; m <<= 1) ss += __shfl_xor(ss, m, 64);
  float rn = rsqrtf(ss + EPSf);
  if (!which) rn *= 0.08838834764831845f;  // DK^-0.5
  cs[base + lane] = v0 * rn;
  cs[base + lane + 64] = v1 * rn;
}

// -------- delta-rule scan v11: one wave/block, 4096 blocks, chunked LDS -----
// Block = (vg 0..63, h, b): 2 v-cols per wave. lane = c2(0..1) + 2*kg(0..31).
// S[4] = state[kg*4 .. +4)[col]. Chunks of SCH=4 steps double-buffered in LDS
// (~8.4 KB -> 16 blocks/CU -> 4 waves/SIMD, 2x the latency hiding of v6).
// Compact per-block-contiguous stores (obuf [bh][vg][s][c2], sftmp).
#define SCH 4
__global__ __launch_bounds__(64, 4) void scan_kernel(
    const float* __restrict__ cs, const float* __restrict__ g_in,
    const float* __restrict__ beta_in, const float* __restrict__ rs0,
    const int* __restrict__ ctx, float* __restrict__ obuf,
    float* __restrict__ sftmp) {
  const int vg = blockIdx.x, h = blockIdx.y, b = blockIdx.z;
  const int bh = b * HVc + h;
  const int lane = threadIdx.x;
  const int kg = lane >> 1;         // 0..31, owns 4 d-rows
  const int c2 = lane & 1;          // col within group
  const int col = vg * 2 + c2;
  const int khead = h >> 1;         // GQA rep=2
  __shared__ float kl[2][SCH * 128];
  __shared__ float ql[2][SCH * 128];
  __shared__ float vl[2][SCH * 2];
  __shared__ float egl[2][SCH];
  __shared__ float btl[2][SCH];
  float S[4];
#pragma unroll
  for (int i = 0; i < 4; ++i)
    S[i] = rs0[((size_t)bh * DKc + kg * 4 + i) * DVc + col];
  const int cl = ctx[b];
  const size_t qgo = (size_t)khead * DKc;
  const size_t kgo = KEYD + (size_t)khead * DKc;
  const size_t vG = 2 * KEYD + (size_t)h * DVc + vg * 2;
  const size_t obase = ((size_t)bh * 64 + vg) * (SEQ * 2);   // contiguous 2KB
  const int r0g = b * SEQ;
  const int kg4 = kg * 4;
  float4 kreg[2], qreg[2];
  float vreg = 0.f, egr = 0.f, btr = 0.f;
  // ---- prologue: load + commit chunk 0
#pragma unroll
  for (int it = 0; it < 2; ++it) {
    int idx = it * 64 + lane, s = idx >> 5, d4 = idx & 31;
    const float* rp = cs + (size_t)(r0g + s) * CONVD;
    kreg[it] = *(const float4*)(rp + kgo + d4 * 4);
    qreg[it] = *(const float4*)(rp + qgo + d4 * 4);
  }
  if (lane < 8)       vreg = cs[(size_t)(r0g + (lane >> 1)) * CONVD + vG + (lane & 1)];
  else if (lane < 12) egr = expf(g_in[(r0g + lane - 8) * HVc + h]);
  else if (lane < 16) btr = beta_in[(r0g + lane - 12) * HVc + h];
#pragma unroll
  for (int it = 0; it < 2; ++it) {
    int idx = it * 64 + lane, s = idx >> 5, d4 = idx & 31;
    *(float4*)&kl[0][s * 128 + d4 * 4] = kreg[it];
    *(float4*)&ql[0][s * 128 + d4 * 4] = qreg[it];
  }
  if (lane < 8)       vl[0][lane] = vreg;
  else if (lane < 12) egl[0][lane - 8] = egr;
  else if (lane < 16) btl[0][lane - 12] = btr;

  const int NCH = SEQ / SCH;  // 64
  for (int c = 0; c < NCH; ++c) {
    const int buf = c & 1;
    // prefetch chunk c+1 into registers (hidden behind this chunk's compute)
    if (c + 1 < NCH) {
      const int r1 = r0g + (c + 1) * SCH;
#pragma unroll
      for (int it = 0; it < 2; ++it) {
        int idx = it * 64 + lane, s = idx >> 5, d4 = idx & 31;
        const float* rp = cs + (size_t)(r1 + s) * CONVD;
        kreg[it] = *(const float4*)(rp + kgo + d4 * 4);
        qreg[it] = *(const float4*)(rp + qgo + d4 * 4);
      }
      if (lane < 8)       vreg = cs[(size_t)(r1 + (lane >> 1)) * CONVD + vG + (lane & 1)];
      else if (lane < 12) egr = expf(g_in[(r1 + lane - 8) * HVc + h]);
      else if (lane < 16) btr = beta_in[(r1 + lane - 12) * HVc + h];
    }
    // compute SCH steps from LDS
#pragma unroll
    for (int s = 0; s < SCH; ++s) {
      const int sg = c * SCH + s;
      const float eg = egl[buf][s], bt = btl[buf][s];
      const float vv = vl[buf][s * 2 + c2];
      const float4 kk = *(const float4*)&kl[buf][s * 128 + kg4];
      const float4 qq = *(const float4*)&ql[buf][s * 128 + kg4];
      if (sg < cl) {
        float a0, a1, a2, a3;
        S[0] *= eg; a0 = kk.x * S[0];
        S[1] *= eg; a1 = kk.y * S[1];
        S[2] *= eg; a2 = kk.z * S[2];
        S[3] *= eg; a3 = kk.w * S[3];
        float p = (a0 + a1) + (a2 + a3);
        p += __shfl_xor(p, 2, 64);
        p += __shfl_xor(p, 4, 64);
        p += __shfl_xor(p, 8, 64);
        p += __shfl_xor(p, 16, 64);
        p += __shfl_xor(p, 32, 64);
        const float delta = (vv - p) * bt;
        float o0, o1, o2, o3;
        S[0] += kk.x * delta; o0 = qq.x * S[0];
        S[1] += kk.y * delta; o1 = qq.y * S[1];
        S[2] += kk.z * delta; o2 = qq.z * S[2];
        S[3] += kk.w * delta; o3 = qq.w * S[3];
        float o = (o0 + o1) + (o2 + o3);
        o += __shfl_xor(o, 2, 64);
        o += __shfl_xor(o, 4, 64);
        o += __shfl_xor(o, 8, 64);
        o += __shfl_xor(o, 16, 64);
        o += __shfl_xor(o, 32, 64);
        if (kg == 0) obuf[obase + sg * 2 + c2] = o;
      } else {
        if (kg == 0) obuf[obase + sg * 2 + c2] = 0.f;
      }
    }
    // commit prefetched chunk to the other LDS buffer
    if (c + 1 < NCH) {
      const int nb = buf ^ 1;
#pragma unroll
      for (int it = 0; it < 2; ++it) {
        int idx = it * 64 + lane, s = idx >> 5, d4 = idx & 31;
        *(float4*)&kl[nb][s * 128 + d4 * 4] = kreg[it];
        *(float4*)&ql[nb][s * 128 + d4 * 4] = qreg[it];
      }
      if (lane < 8)       vl[nb][lane] = vreg;
      else if (lane < 12) egl[nb][lane - 8] = egr;
      else if (lane < 16) btl[nb][lane - 12] = btr;
    }
  }
  // final state to compact per-block-contiguous buffer [bh][vg][dk][c2]
  const size_t sb = (((size_t)bh * 64 + vg) * DKc + kg4) * 2 + c2;
#pragma unroll
  for (int i = 0; i < 4; ++i)
    sftmp[sb + i * 2] = S[i];
}

// -------- sfin transpose: compact [bh][vg][dk][c2] -> out [bh][dk][dv] ------
__global__ __launch_bounds__(128) void sfin_tr_kernel(
    const float* __restrict__ sftmp, float* __restrict__ out_sf) {
  const int dk = blockIdx.x;
  const int bh = blockIdx.y;
  const int dv = threadIdx.x;
  out_sf[((size_t)bh * DKc + dk) * DVc + dv] =
      sftmp[(((size_t)bh * 64 + (dv >> 1)) * DKc + dk) * 2 + (dv & 1)];
}

// -------- gated RMSNorm over DV + SiLU(z): obuf -> bf16 A-matrix of GEMM3 ---
__global__ __launch_bounds__(64) void normgate_kernel(
    const float* __restrict__ obuf, const float* __restrict__ zbuf,
    const float* __restrict__ norm_w, short* __restrict__ o16) {
  int bx = blockIdx.x;   // row*32 + h
  int h = bx & 31;
  int row = bx >> 5;
  int b = row >> 8;      // row / SEQ
  int s = row & (SEQ - 1);
  int lane = threadIdx.x;
  // obuf layout [bh][vg64][s][c2]; dv = vg*2 + c2
  size_t ob = ((size_t)(b * HVc + h) * 64 + (lane >> 1)) * (SEQ * 2) + s * 2 + (lane & 1);
  size_t zb = (size_t)row * VALD + h * DVc;
  float o0 = obuf[ob];
  float o1 = obuf[ob + 32 * (SEQ * 2)];
  float ss = o0 * o0 + o1 * o1;
#pragma unroll
  for (int m = 1; m < 64; m <<= 1) ss += __shfl_xor(ss, m, 64);
  float rms = rsqrtf(ss * (1.f / 128.f) + EPSf);
  float z0 = zbuf[zb + lane];
  float z1 = zbuf[zb + lane + 64];
  o16[zb + lane]      = f2bf(o0 * rms * norm_w[lane]      * (z0 / (1.f + expf(-z0))));
  o16[zb + lane + 64] = f2bf(o1 * rms * norm_w[lane + 64] * (z1 / (1.f + expf(-z1))));
}

extern "C" void kernel_launch(void* const* d_in, const int* in_sizes, int n_in,
                              void* d_out, int out_size, void* d_ws, size_t ws_size,
                              hipStream_t stream) {
  const float* hs        = (const float*)d_in[0];
  const float* conv_st   = (const float*)d_in[1];
  const float* rec_st    = (const float*)d_in[2];
  const int*   ctx       = (const int*)d_in[3];
  const float* W_qkv     = (const float*)d_in[4];
  const float* W_z       = (const float*)d_in[5];
  const float* W_b       = (const float*)d_in[6];
  const float* W_a       = (const float*)d_in[7];
  const float* conv_w    = (const float*)d_in[8];
  const float* conv_b    = (const float*)d_in[9];
  const float* A_log     = (const float*)d_in[10];
  const float* dt_bias   = (const float*)d_in[11];
  const float* norm_w    = (const float*)d_in[12];
  const float* W_out     = (const float*)d_in[13];

  float* out0   = (float*)d_out;                          // [B,S,H]
  float* out_cv = out0 + (size_t)MM * HH;                 // [B,CONVD,K-1]
  float* out_sf = out_cv + (size_t)BB * CONVD * (KC - 1); // [B,HV,DK,DV]

  // Workspace layout (time-aliased; ~54 MB):
  //  [0,16M)   mixed (fp32 GEMM1 out; later obuf 8M + sftmp 4M)
  //  [16M,48M) wt: weight transpose region (Wqkv_t 32M / Wz_t 16M / Wout_t 16M)
  //            cs aliases [16M,32M); zbuf at [32M,40M)
  //  [48M,..)  gbuf, betab, hs16 (2M), o16 (4M)
  char*  base  = (char*)d_ws;
  float* mixed = (float*)base;
  char*  wtB   = base + (size_t)MM * CONVD * 4;
  short* wt    = (short*)wtB;
  float* cs    = (float*)wtB;
  float* zbuf  = (float*)(wtB + (size_t)MM * CONVD * 4);
  float* gbuf  = (float*)(wtB + (size_t)CONVD * HH * 2);
  float* betab = gbuf + (size_t)MM * HVc;
  short* hs16  = (short*)(betab + (size_t)MM * HVc);
  short* o16   = hs16 + (size_t)MM * HH;
  float* obuf  = mixed;
  float* sftmp = mixed + (size_t)MM * VALD;

  // 0a) hs -> bf16
  f2bf_kernel<<<(MM * HH / 8) / 256, 256, 0, stream>>>(hs, hs16);
  // 0b) W_qkv -> Wqkv_t [CONVD][HH] bf16
  trconv_kernel<<<dim3(CONVD / 32, HH / 64), 256, 0, stream>>>(W_qkv, wt, HH, CONVD);
  // 1) mixed = hs16 @ Wqkv_t^T, split-K x2 (atomic; zero first)
  zerof_kernel<<<(MM * CONVD / 4) / 256, 256, 0, stream>>>(mixed);
  gemm_bf16<<<dim3(CONVD / 128, MM / 64, 2), 256, 0, stream>>>(
      hs16, wt, mixed, MM, CONVD, HH, HH, HH / 2, 1);
  // 2a) W_z -> Wz_t [VALD][HH] bf16 (Wqkv_t dead)
  trconv_kernel<<<dim3(VALD / 32, HH / 64), 256, 0, stream>>>(W_z, wt, HH, VALD);
  // 2b) z = hs16 @ Wz_t^T, split-K x2
  zerof_kernel<<<(MM * VALD / 4) / 256, 256, 0, stream>>>(zbuf);
  gemm_bf16<<<dim3(VALD / 128, MM / 64, 2), 256, 0, stream>>>(
      hs16, wt, zbuf, MM, VALD, HH, HH, HH / 2, 1);
  // 3) b,a projections + gating
  proj_ab_kernel<<<MM, 256, 0, stream>>>(hs, W_b, W_a, A_log, dt_bias, gbuf, betab);
  // 4) conv + silu (mixed -> cs; overwrites dead Wz_t)
  conv_par_kernel<<<dim3(CONVD / 256, SEQ / CCH, BB), 256, 0, stream>>>(
      mixed, conv_st, conv_w, conv_b, cs);
  // 5) conv_state_out from raw mixed
  conv_state_out_kernel<<<(BB * CONVD * (KC - 1)) / 256, 256, 0, stream>>>(mixed, out_cv);
  // 6) l2norm q,k in place on cs
  l2norm_kernel<<<MM * HKc * 2, 64, 0, stream>>>(cs);
  // 7) delta-rule scan v11: 4096 one-wave blocks (vg 0..63), SCH=4 chunks
  scan_kernel<<<dim3(64, HVc, BB), 64, 0, stream>>>(cs, gbuf, betab, rec_st, ctx, obuf, sftmp);
  // 7b) transpose compact Sfin -> out_sf [B,HV,DK,DV]
  sfin_tr_kernel<<<dim3(DKc, BB * HVc), 128, 0, stream>>>(sftmp, out_sf);
  // 8) gated RMSNorm + silu(z): obuf,zbuf -> o16 (bf16 A of GEMM3)
  normgate_kernel<<<MM * HVc, 64, 0, stream>>>(obuf, zbuf, norm_w, o16);
  // 9a) W_out -> Wout_t [HH][VALD] bf16 (overwrites dead cs)
  trconv_kernel<<<dim3(HH / 32, VALD / 64), 256, 0, stream>>>(W_out, wt, VALD, HH);
  // 9b) output = o16 @ Wout_t^T, split-K x4
  zerof_kernel<<<(MM * HH / 4) / 256, 256, 0, stream>>>(out0);
  gemm_bf16<<<dim3(HH / 128, MM / 64, 4), 256, 0, stream>>>(
      o16, wt, out0, MM, HH, VALD, VALD, VALD / 4, 1);
}

// Round 12
// 530.669 us; speedup vs baseline: 1.0580x; 1.0580x over previous
//
#include <hip/hip_runtime.h>
#include <hip/hip_bf16.h>

// Problem constants
#define BB     2
#define SEQ    256
#define HH     2048
#define HKc    16
#define HVc    32
#define DKc    128
#define DVc    128
#define KC     4
#define KEYD   2048      // HKc*DKc
#define VALD   4096      // HVc*DVc
#define CONVD  8192      // 2*KEYD + VALD
#define MM     (BB*SEQ)  // 512
#define EPSf   1e-6f

typedef __attribute__((ext_vector_type(8))) short short8;
typedef __attribute__((ext_vector_type(4))) short short4v;
typedef __attribute__((ext_vector_type(4))) float floatx4;

__device__ __forceinline__ short f2bf(float f) {
  union { float f; unsigned u; } v; v.f = f;
  unsigned r = v.u + 0x7fffu + ((v.u >> 16) & 1u);   // RNE
  return (short)(r >> 16);
}

// -------- zero-fill (float4 per thread) -------------------------------------
__global__ __launch_bounds__(256) void zerof_kernel(float* __restrict__ p) {
  float4 z; z.x = 0.f; z.y = 0.f; z.z = 0.f; z.w = 0.f;
  *(float4*)&p[(size_t)(blockIdx.x * 256 + threadIdx.x) * 4] = z;
}

// -------- transpose-convert: W[K][N] fp32 -> Wt[N][K] bf16 ------------------
// 64k x 32n tile; writes are 32 FULL 128B lines per block.
__global__ __launch_bounds__(256) void trconv_kernel(
    const float* __restrict__ W, short* __restrict__ Wt, int K, int N) {
  __shared__ float ls[64][33];
  const int n0 = blockIdx.x * 32;
  const int k0 = blockIdx.y * 64;
  const int t = threadIdx.x;
#pragma unroll
  for (int it = 0; it < 2; ++it) {
    const int kr = (t >> 3) + it * 32;
    const int c4 = (t & 7) * 4;
    const float4 f = *(const float4*)&W[(size_t)(k0 + kr) * N + n0 + c4];
    ls[kr][c4] = f.x; ls[kr][c4 + 1] = f.y; ls[kr][c4 + 2] = f.z; ls[kr][c4 + 3] = f.w;
  }
  __syncthreads();
  const int r = t >> 3;           // 0..31 n-row
  const int kc = (t & 7) * 8;     // 0..56 k-chunk
  short8 s;
#pragma unroll
  for (int j = 0; j < 8; ++j) s[j] = f2bf(ls[kc + j][r]);
  *(short8*)&Wt[(size_t)(n0 + r) * K + k0 + kc] = s;
}

// -------- elementwise fp32 -> bf16 (8 per thread) ---------------------------
__global__ __launch_bounds__(256) void f2bf_kernel(
    const float* __restrict__ in, short* __restrict__ out) {
  const int i = blockIdx.x * 256 + threadIdx.x;
  const float4 a = *(const float4*)&in[(size_t)i * 8];
  const float4 b = *(const float4*)&in[(size_t)i * 8 + 4];
  short8 s;
  s[0] = f2bf(a.x); s[1] = f2bf(a.y); s[2] = f2bf(a.z); s[3] = f2bf(a.w);
  s[4] = f2bf(b.x); s[5] = f2bf(b.y); s[6] = f2bf(b.z); s[7] = f2bf(b.w);
  *(short8*)&out[(size_t)i * 8] = s;
}

// ---------- MFMA bf16 GEMM: C[M,N] (+)= A[M,K](bf16,lda) * Bt[N,K]^T --------
// Block tile 64m x 128n, BK=64 (16 MFMA per barrier-pair), 256 threads =
// 4 waves (2x2), wave = 32m x 64n. Register prefetch of next K-step during
// MFMA. Split-K via blockIdx.z (atom=1 -> atomicAdd into pre-zeroed C).
#define PAD2 72   // shorts per LDS row: 64 data + 8 pad (144 B, 16B-aligned)
__global__ __launch_bounds__(256) void gemm_bf16(
    const short* __restrict__ A, const short* __restrict__ Bt,
    float* __restrict__ C, int M, int N, int Kd, int lda, int klen, int atom) {
  __shared__ short As[64 * PAD2];    // 9216 B
  __shared__ short Bs[128 * PAD2];   // 18432 B
  const int tid = threadIdx.x;
  const int wave = tid >> 6, lane = tid & 63;
  const int wm = (wave >> 1) * 32, wn = (wave & 1) * 64;
  const int bm = blockIdx.y * 64, bn = blockIdx.x * 128;
  const int koff = blockIdx.z * klen;
  floatx4 acc[2][4] = {};
  const int sr = tid >> 3;            // 0..31 row base
  const int skc = (tid & 7) * 8;      // 0..56 k-chunk (8 shorts)
  const int fm = lane & 15, fq = (lane >> 4) * 8;
  const short* Ap = A  + koff + skc;
  const short* Bp = Bt + koff + skc;
  short8 pa[2], pb[4];
#pragma unroll
  for (int it = 0; it < 2; ++it)
    pa[it] = *(const short8*)(Ap + (size_t)(bm + sr + it * 32) * lda);
#pragma unroll
  for (int it = 0; it < 4; ++it)
    pb[it] = *(const short8*)(Bp + (size_t)(bn + sr + it * 32) * Kd);
  for (int k0 = 0; k0 < klen; k0 += 64) {
#pragma unroll
    for (int it = 0; it < 2; ++it)
      *(short8*)&As[(sr + it * 32) * PAD2 + skc] = pa[it];
#pragma unroll
    for (int it = 0; it < 4; ++it)
      *(short8*)&Bs[(sr + it * 32) * PAD2 + skc] = pb[it];
    __syncthreads();
    if (k0 + 64 < klen) {
#pragma unroll
      for (int it = 0; it < 2; ++it)
        pa[it] = *(const short8*)(Ap + (size_t)(bm + sr + it * 32) * lda + k0 + 64);
#pragma unroll
      for (int it = 0; it < 4; ++it)
        pb[it] = *(const short8*)(Bp + (size_t)(bn + sr + it * 32) * Kd + k0 + 64);
    }
    short8 af[2][2], bfr[2][4];
#pragma unroll
    for (int hh = 0; hh < 2; ++hh) {
#pragma unroll
      for (int i = 0; i < 2; ++i)
        af[hh][i] = *(const short8*)&As[(wm + i * 16 + fm) * PAD2 + hh * 32 + fq];
#pragma unroll
      for (int j = 0; j < 4; ++j)
        bfr[hh][j] = *(const short8*)&Bs[(wn + j * 16 + fm) * PAD2 + hh * 32 + fq];
    }
#pragma unroll
    for (int hh = 0; hh < 2; ++hh)
#pragma unroll
      for (int i = 0; i < 2; ++i)
#pragma unroll
        for (int j = 0; j < 4; ++j)
          acc[i][j] = __builtin_amdgcn_mfma_f32_16x16x32_bf16(af[hh][i], bfr[hh][j], acc[i][j], 0, 0, 0);
    __syncthreads();
  }
  const int cn = lane & 15, cr0 = (lane >> 4) * 4;
  if (atom) {
#pragma unroll
    for (int i = 0; i < 2; ++i)
#pragma unroll
      for (int j = 0; j < 4; ++j)
#pragma unroll
        for (int r = 0; r < 4; ++r)
          atomicAdd(&C[(size_t)(bm + wm + i * 16 + cr0 + r) * N + bn + wn + j * 16 + cn],
                    acc[i][j][r]);
  } else {
#pragma unroll
    for (int i = 0; i < 2; ++i)
#pragma unroll
      for (int j = 0; j < 4; ++j)
#pragma unroll
        for (int r = 0; r < 4; ++r)
          C[(size_t)(bm + wm + i * 16 + cr0 + r) * N + bn + wn + j * 16 + cn] = acc[i][j][r];
  }
}

// -------- b/a projections fused with gating --------
__global__ __launch_bounds__(256) void proj_ab_kernel(
    const float* __restrict__ hs, const float* __restrict__ Wb,
    const float* __restrict__ Wa, const float* __restrict__ A_log,
    const float* __restrict__ dt_bias, float* __restrict__ g_out,
    float* __restrict__ beta_out) {
  __shared__ float xs[HH];
  __shared__ float part[4][64];
  const int row = blockIdx.x;
  const int t = threadIdx.x;
  for (int i = t; i < HH; i += 256) xs[i] = hs[(size_t)row * HH + i];
  __syncthreads();
  const int j = t & 63;
  const int kc = t >> 6;
  const float* W = (j < 32) ? Wb : Wa;
  const int jj = j & 31;
  float p = 0.f;
  const int k0 = kc * 512;
#pragma unroll 8
  for (int k = k0; k < k0 + 512; ++k) p += xs[k] * W[k * 32 + jj];
  part[kc][j] = p;
  __syncthreads();
  if (t < 64) {
    float dot = part[0][t] + part[1][t] + part[2][t] + part[3][t];
    if (t < 32) {
      beta_out[row * HVc + t] = 1.f / (1.f + expf(-dot));
    } else {
      int h = t - 32;
      float x = dot + dt_bias[h];
      float sp = (x > 20.f) ? x : log1pf(expf(x));
      g_out[row * HVc + h] = -expf(A_log[h]) * sp;
    }
  }
}

// -------- depthwise causal conv (K=4) + SiLU, parallel over s-chunks --------
#define CCH 16
__global__ __launch_bounds__(256) void conv_par_kernel(
    const float* __restrict__ mixed, const float* __restrict__ conv_state,
    const float* __restrict__ conv_w, const float* __restrict__ conv_b,
    float* __restrict__ cs) {
  const int c = blockIdx.x * 256 + threadIdx.x;   // channel
  const int s0 = blockIdx.y * CCH;
  const int b = blockIdx.z;
  const float4 w4 = *(const float4*)&conv_w[c * KC];
  const float bias = conv_b[c];
  float r0, r1, r2;
  if (s0 == 0) {
    size_t sb = (size_t)(b * CONVD + c) * (KC - 1);
    r0 = conv_state[sb + 0]; r1 = conv_state[sb + 1]; r2 = conv_state[sb + 2];
  } else {
    r0 = mixed[((size_t)(b * SEQ + s0 - 3)) * CONVD + c];
    r1 = mixed[((size_t)(b * SEQ + s0 - 2)) * CONVD + c];
    r2 = mixed[((size_t)(b * SEQ + s0 - 1)) * CONVD + c];
  }
#pragma unroll
  for (int s = s0; s < s0 + CCH; ++s) {
    size_t off = ((size_t)(b * SEQ + s)) * CONVD + c;
    float x = mixed[off];
    float acc = bias + r0 * w4.x + r1 * w4.y + r2 * w4.z + x * w4.w;
    cs[off] = acc / (1.f + expf(-acc));
    r0 = r1; r1 = r2; r2 = x;
  }
}

// -------- conv_state_out: last K-1 raw rows of mixed, [B,C,K-1] fp32 --------
__global__ __launch_bounds__(256) void conv_state_out_kernel(
    const float* __restrict__ mixed, float* __restrict__ out2) {
  int idx = blockIdx.x * 256 + threadIdx.x;  // over BB*CONVD*(KC-1)
  int t = idx % (KC - 1);
  int c = (idx / (KC - 1)) & (CONVD - 1);
  int b = idx / ((KC - 1) * CONVD);
  out2[idx] = mixed[((size_t)(b * SEQ + SEQ - (KC - 1) + t)) * CONVD + c];
}

// -------- per-head l2norm of q (scaled by DK^-0.5) and k, IN PLACE on cs ----
__global__ __launch_bounds__(64) void l2norm_kernel(float* __restrict__ cs) {
  int bx = blockIdx.x;          // row*32 + head*2 + which
  int which = bx & 1;
  int head = (bx >> 1) & 15;
  int row = bx >> 5;
  int lane = threadIdx.x;
  size_t base = (size_t)row * CONVD + (size_t)which * KEYD + head * DKc;
  float v0 = cs[base + lane];
  float v1 = cs[base + lane + 64];
  float ss = v0 * v0 + v1 * v1;
#pragma unroll
  for (int m = 1; m < 64; m <<= 1) ss += __shfl_xor(ss, m, 64);
  float rn = rsqrtf(ss + EPSf);
  if (!which) rn *= 0.08838834764831845f;  // DK^-0.5
  cs[base + lane] = v0 * rn;
  cs[base + lane + 64] = v1 * rn;
}

// -------- delta-rule scan v13: v6 skeleton + deferred-o interleaved reduce --
// Block = (vg 0..31, h, b): 4 v-cols per wave. lane = c4(0..3) + 4*kg(0..15).
// S[8] = state[kg*8 .. +8)[col]. Chunks of SCH=8 double-buffered in LDS.
// KEY CHANGE vs v6: only the p-reduce gates the recurrence; the o-reduce of
// step s is DEFERRED and its 4 shfl stages interleave with step s+1's
// p-reduce (two independent DS-pipe chains share one latency window ->
// serial shuffle latency per step halves ~960->~480cy). Masked steps are
// branch-free: eg<-1, bt<-0 leaves S unchanged; o partial forced to 0.
#define SCH 8
__global__ __launch_bounds__(64, 2) void scan_kernel(
    const float* __restrict__ cs, const float* __restrict__ g_in,
    const float* __restrict__ beta_in, const float* __restrict__ rs0,
    const int* __restrict__ ctx, float* __restrict__ obuf,
    float* __restrict__ sftmp) {
  const int vg = blockIdx.x, h = blockIdx.y, b = blockIdx.z;
  const int bh = b * HVc + h;
  const int lane = threadIdx.x;
  const int kg = lane >> 2;         // k-sixteenth (0..15), owns 8 d-rows
  const int c4 = lane & 3;          // col within group
  const int col = vg * 4 + c4;
  const int khead = h >> 1;         // GQA rep=2
  __shared__ float kl[2][SCH * 128];
  __shared__ float ql[2][SCH * 128];
  __shared__ float vl[2][SCH * 4];
  __shared__ float egl[2][SCH];
  __shared__ float btl[2][SCH];
  float S[8];
#pragma unroll
  for (int i = 0; i < 8; ++i)
    S[i] = rs0[((size_t)bh * DKc + kg * 8 + i) * DVc + col];
  const int cl = ctx[b];
  const size_t qgo = (size_t)khead * DKc;
  const size_t kgo = KEYD + (size_t)khead * DKc;
  const size_t vG = 2 * KEYD + (size_t)h * DVc + vg * 4;
  const size_t obase = ((size_t)bh * 32 + vg) * (SEQ * 4);   // contiguous 4KB
  const int r0g = b * SEQ;
  const int kg8 = kg * 8;
  float4 kreg[4], qreg[4], vreg;
  float egr = 0.f, btr = 0.f;
  // ---- prologue: load + commit chunk 0
#pragma unroll
  for (int it = 0; it < 4; ++it) {
    int idx = it * 64 + lane, s = idx >> 5, d4 = idx & 31;
    const float* rp = cs + (size_t)(r0g + s) * CONVD;
    kreg[it] = *(const float4*)(rp + kgo + d4 * 4);
    qreg[it] = *(const float4*)(rp + qgo + d4 * 4);
  }
  if (lane < 8)       vreg = *(const float4*)(cs + (size_t)(r0g + lane) * CONVD + vG);
  else if (lane < 16) egr = expf(g_in[(r0g + lane - 8) * HVc + h]);
  else if (lane < 24) btr = beta_in[(r0g + lane - 16) * HVc + h];
#pragma unroll
  for (int it = 0; it < 4; ++it) {
    int idx = it * 64 + lane, s = idx >> 5, d4 = idx & 31;
    *(float4*)&kl[0][s * 128 + d4 * 4] = kreg[it];
    *(float4*)&ql[0][s * 128 + d4 * 4] = qreg[it];
  }
  if (lane < 8)       *(float4*)&vl[0][lane * 4] = vreg;
  else if (lane < 16) egl[0][lane - 8] = egr;
  else if (lane < 24) btl[0][lane - 16] = btr;

  float opend = 0.f;        // deferred lane-local o partial of previous step
  const int NCH = SEQ / SCH;  // 32
  for (int c = 0; c < NCH; ++c) {
    const int buf = c & 1;
    // prefetch chunk c+1 into registers (hidden behind this chunk's compute)
    if (c + 1 < NCH) {
      const int r1 = r0g + (c + 1) * SCH;
#pragma unroll
      for (int it = 0; it < 4; ++it) {
        int idx = it * 64 + lane, s = idx >> 5, d4 = idx & 31;
        const float* rp = cs + (size_t)(r1 + s) * CONVD;
        kreg[it] = *(const float4*)(rp + kgo + d4 * 4);
        qreg[it] = *(const float4*)(rp + qgo + d4 * 4);
      }
      if (lane < 8)       vreg = *(const float4*)(cs + (size_t)(r1 + lane) * CONVD + vG);
      else if (lane < 16) egr = expf(g_in[(r1 + lane - 8) * HVc + h]);
      else if (lane < 24) btr = beta_in[(r1 + lane - 16) * HVc + h];
    }
    // compute SCH steps from LDS
#pragma unroll
    for (int s = 0; s < SCH; ++s) {
      const int sg = c * SCH + s;
      const bool act = sg < cl;                      // wave-uniform
      const float eg = act ? egl[buf][s] : 1.f;      // eg=1,bt=0 => S frozen
      const float bt = act ? btl[buf][s] : 0.f;
      const float vv = vl[buf][s * 4 + c4];
      const float4* k4 = (const float4*)&kl[buf][s * 128 + kg8];
      const float4* q4 = (const float4*)&ql[buf][s * 128 + kg8];
      const float4 kk0 = k4[0], kk1 = k4[1];
      float a0, a1, a2, a3;
      S[0] *= eg; a0 = kk0.x * S[0];
      S[1] *= eg; a1 = kk0.y * S[1];
      S[2] *= eg; a2 = kk0.z * S[2];
      S[3] *= eg; a3 = kk0.w * S[3];
      S[4] *= eg; a0 += kk1.x * S[4];
      S[5] *= eg; a1 += kk1.y * S[5];
      S[6] *= eg; a2 += kk1.z * S[6];
      S[7] *= eg; a3 += kk1.w * S[7];
      float p = (a0 + a1) + (a2 + a3);
      float oo = opend;                 // previous step's o, lane-local
      // interleaved independent 4-stage chains (compiler emits counted waits)
      p  += __shfl_xor(p, 4, 64);   oo += __shfl_xor(oo, 4, 64);
      p  += __shfl_xor(p, 8, 64);   oo += __shfl_xor(oo, 8, 64);
      p  += __shfl_xor(p, 16, 64);  oo += __shfl_xor(oo, 16, 64);
      p  += __shfl_xor(p, 32, 64);  oo += __shfl_xor(oo, 32, 64);
      if (kg == 0 && sg > 0) obuf[obase + (sg - 1) * 4 + c4] = oo;
      const float delta = (vv - p) * bt;
      const float4 qq0 = q4[0], qq1 = q4[1];
      float o0, o1, o2, o3;
      S[0] += kk0.x * delta; o0 = qq0.x * S[0];
      S[1] += kk0.y * delta; o1 = qq0.y * S[1];
      S[2] += kk0.z * delta; o2 = qq0.z * S[2];
      S[3] += kk0.w * delta; o3 = qq0.w * S[3];
      S[4] += kk1.x * delta; o0 += qq1.x * S[4];
      S[5] += kk1.y * delta; o1 += qq1.y * S[5];
      S[6] += kk1.z * delta; o2 += qq1.z * S[6];
      S[7] += kk1.w * delta; o3 += qq1.w * S[7];
      opend = act ? (o0 + o1) + (o2 + o3) : 0.f;     // masked step -> o = 0
    }
    // commit prefetched chunk to the other LDS buffer
    if (c + 1 < NCH) {
      const int nb = buf ^ 1;
#pragma unroll
      for (int it = 0; it < 4; ++it) {
        int idx = it * 64 + lane, s = idx >> 5, d4 = idx & 31;
        *(float4*)&kl[nb][s * 128 + d4 * 4] = kreg[it];
        *(float4*)&ql[nb][s * 128 + d4 * 4] = qreg[it];
      }
      if (lane < 8)       *(float4*)&vl[nb][lane * 4] = vreg;
      else if (lane < 16) egl[nb][lane - 8] = egr;
      else if (lane < 24) btl[nb][lane - 16] = btr;
    }
  }
  // flush the last step's deferred o
  {
    float oo = opend;
    oo += __shfl_xor(oo, 4, 64);
    oo += __shfl_xor(oo, 8, 64);
    oo += __shfl_xor(oo, 16, 64);
    oo += __shfl_xor(oo, 32, 64);
    if (kg == 0) obuf[obase + (SEQ - 1) * 4 + c4] = oo;
  }
  // final state to compact per-block-contiguous buffer [bh][vg][dk][c4]
  const size_t sb = (((size_t)bh * 32 + vg) * DKc + kg8) * 4 + c4;
#pragma unroll
  for (int i = 0; i < 8; ++i)
    sftmp[sb + i * 4] = S[i];
}

// -------- sfin transpose: compact [bh][vg][dk][c4] -> out [bh][dk][dv] ------
__global__ __launch_bounds__(128) void sfin_tr_kernel(
    const float* __restrict__ sftmp, float* __restrict__ out_sf) {
  const int dk = blockIdx.x;
  const int bh = blockIdx.y;
  const int dv = threadIdx.x;
  out_sf[((size_t)bh * DKc + dk) * DVc + dv] =
      sftmp[(((size_t)bh * 32 + (dv >> 2)) * DKc + dk) * 4 + (dv & 3)];
}

// -------- gated RMSNorm over DV + SiLU(z): obuf -> bf16 A-matrix of GEMM3 ---
__global__ __launch_bounds__(64) void normgate_kernel(
    const float* __restrict__ obuf, const float* __restrict__ zbuf,
    const float* __restrict__ norm_w, short* __restrict__ o16) {
  int bx = blockIdx.x;   // row*32 + h
  int h = bx & 31;
  int row = bx >> 5;
  int b = row >> 8;      // row / SEQ
  int s = row & (SEQ - 1);
  int lane = threadIdx.x;
  size_t ob = ((size_t)(b * HVc + h) * 32 + (lane >> 2)) * (SEQ * 4) + s * 4 + (lane & 3);
  size_t zb = (size_t)row * VALD + h * DVc;
  float o0 = obuf[ob];
  float o1 = obuf[ob + 16 * (SEQ * 4)];
  float ss = o0 * o0 + o1 * o1;
#pragma unroll
  for (int m = 1; m < 64; m <<= 1) ss += __shfl_xor(ss, m, 64);
  float rms = rsqrtf(ss * (1.f / 128.f) + EPSf);
  float z0 = zbuf[zb + lane];
  float z1 = zbuf[zb + lane + 64];
  o16[zb + lane]      = f2bf(o0 * rms * norm_w[lane]      * (z0 / (1.f + expf(-z0))));
  o16[zb + lane + 64] = f2bf(o1 * rms * norm_w[lane + 64] * (z1 / (1.f + expf(-z1))));
}

extern "C" void kernel_launch(void* const* d_in, const int* in_sizes, int n_in,
                              void* d_out, int out_size, void* d_ws, size_t ws_size,
                              hipStream_t stream) {
  const float* hs        = (const float*)d_in[0];
  const float* conv_st   = (const float*)d_in[1];
  const float* rec_st    = (const float*)d_in[2];
  const int*   ctx       = (const int*)d_in[3];
  const float* W_qkv     = (const float*)d_in[4];
  const float* W_z       = (const float*)d_in[5];
  const float* W_b       = (const float*)d_in[6];
  const float* W_a       = (const float*)d_in[7];
  const float* conv_w    = (const float*)d_in[8];
  const float* conv_b    = (const float*)d_in[9];
  const float* A_log     = (const float*)d_in[10];
  const float* dt_bias   = (const float*)d_in[11];
  const float* norm_w    = (const float*)d_in[12];
  const float* W_out     = (const float*)d_in[13];

  float* out0   = (float*)d_out;                          // [B,S,H]
  float* out_cv = out0 + (size_t)MM * HH;                 // [B,CONVD,K-1]
  float* out_sf = out_cv + (size_t)BB * CONVD * (KC - 1); // [B,HV,DK,DV]

  // Workspace layout (time-aliased; ~54 MB):
  //  [0,16M)   mixed (fp32 GEMM1 out; later obuf 8M + sftmp 4M)
  //  [16M,48M) wt: weight transpose region (Wqkv_t 32M / Wz_t 16M / Wout_t 16M)
  //            cs aliases [16M,32M); zbuf at [32M,40M)
  //  [48M,..)  gbuf, betab, hs16 (2M), o16 (4M)
  char*  base  = (char*)d_ws;
  float* mixed = (float*)base;
  char*  wtB   = base + (size_t)MM * CONVD * 4;
  short* wt    = (short*)wtB;
  float* cs    = (float*)wtB;
  float* zbuf  = (float*)(wtB + (size_t)MM * CONVD * 4);
  float* gbuf  = (float*)(wtB + (size_t)CONVD * HH * 2);
  float* betab = gbuf + (size_t)MM * HVc;
  short* hs16  = (short*)(betab + (size_t)MM * HVc);
  short* o16   = hs16 + (size_t)MM * HH;
  float* obuf  = mixed;
  float* sftmp = mixed + (size_t)MM * VALD;

  // 0a) hs -> bf16
  f2bf_kernel<<<(MM * HH / 8) / 256, 256, 0, stream>>>(hs, hs16);
  // 0b) W_qkv -> Wqkv_t [CONVD][HH] bf16
  trconv_kernel<<<dim3(CONVD / 32, HH / 64), 256, 0, stream>>>(W_qkv, wt, HH, CONVD);
  // 1) mixed = hs16 @ Wqkv_t^T, split-K x2 (atomic; zero first)
  zerof_kernel<<<(MM * CONVD / 4) / 256, 256, 0, stream>>>(mixed);
  gemm_bf16<<<dim3(CONVD / 128, MM / 64, 2), 256, 0, stream>>>(
      hs16, wt, mixed, MM, CONVD, HH, HH, HH / 2, 1);
  // 2a) W_z -> Wz_t [VALD][HH] bf16 (Wqkv_t dead)
  trconv_kernel<<<dim3(VALD / 32, HH / 64), 256, 0, stream>>>(W_z, wt, HH, VALD);
  // 2b) z = hs16 @ Wz_t^T, split-K x2
  zerof_kernel<<<(MM * VALD / 4) / 256, 256, 0, stream>>>(zbuf);
  gemm_bf16<<<dim3(VALD / 128, MM / 64, 2), 256, 0, stream>>>(
      hs16, wt, zbuf, MM, VALD, HH, HH, HH / 2, 1);
  // 3) b,a projections + gating
  proj_ab_kernel<<<MM, 256, 0, stream>>>(hs, W_b, W_a, A_log, dt_bias, gbuf, betab);
  // 4) conv + silu (mixed -> cs; overwrites dead Wz_t)
  conv_par_kernel<<<dim3(CONVD / 256, SEQ / CCH, BB), 256, 0, stream>>>(
      mixed, conv_st, conv_w, conv_b, cs);
  // 5) conv_state_out from raw mixed
  conv_state_out_kernel<<<(BB * CONVD * (KC - 1)) / 256, 256, 0, stream>>>(mixed, out_cv);
  // 6) l2norm q,k in place on cs
  l2norm_kernel<<<MM * HKc * 2, 64, 0, stream>>>(cs);
  // 7) delta-rule scan v13: v6 skeleton + deferred-o interleaved reduce
  scan_kernel<<<dim3(32, HVc, BB), 64, 0, stream>>>(cs, gbuf, betab, rec_st, ctx, obuf, sftmp);
  // 7b) transpose compact Sfin -> out_sf [B,HV,DK,DV]
  sfin_tr_kernel<<<dim3(DKc, BB * HVc), 128, 0, stream>>>(sftmp, out_sf);
  // 8) gated RMSNorm + silu(z): obuf,zbuf -> o16 (bf16 A of GEMM3)
  normgate_kernel<<<MM * HVc, 64, 0, stream>>>(obuf, zbuf, norm_w, o16);
  // 9a) W_out -> Wout_t [HH][VALD] bf16 (overwrites dead cs)
  trconv_kernel<<<dim3(HH / 32, VALD / 64), 256, 0, stream>>>(W_out, wt, VALD, HH);
  // 9b) output = o16 @ Wout_t^T, split-K x4
  zerof_kernel<<<(MM * HH / 4) / 256, 256, 0, stream>>>(out0);
  gemm_bf16<<<dim3(HH / 128, MM / 64, 4), 256, 0, stream>>>(
      o16, wt, out0, MM, HH, VALD, VALD, VALD / 4, 1);
}

// Round 13
// 508.641 us; speedup vs baseline: 1.1038x; 1.0433x over previous
//
#include <hip/hip_runtime.h>
#include <hip/hip_bf16.h>

// Problem constants
#define BB     2
#define SEQ    256
#define HH     2048
#define HKc    16
#define HVc    32
#define DKc    128
#define DVc    128
#define KC     4
#define KEYD   2048      // HKc*DKc
#define VALD   4096      // HVc*DVc
#define CONVD  8192      // 2*KEYD + VALD
#define MM     (BB*SEQ)  // 512
#define EPSf   1e-6f

typedef __attribute__((ext_vector_type(8))) short short8;
typedef __attribute__((ext_vector_type(4))) short short4v;
typedef __attribute__((ext_vector_type(4))) float floatx4;

__device__ __forceinline__ short f2bf(float f) {
  union { float f; unsigned u; } v; v.f = f;
  unsigned r = v.u + 0x7fffu + ((v.u >> 16) & 1u);   // RNE
  return (short)(r >> 16);
}

// -------- zero-fill (float4 per thread) -------------------------------------
__global__ __launch_bounds__(256) void zerof_kernel(float* __restrict__ p) {
  float4 z; z.x = 0.f; z.y = 0.f; z.z = 0.f; z.w = 0.f;
  *(float4*)&p[(size_t)(blockIdx.x * 256 + threadIdx.x) * 4] = z;
}

// -------- transpose-convert: W[K][N] fp32 -> Wt[N][K] bf16 ------------------
// 64k x 32n tile; writes are 32 FULL 128B lines per block.
__global__ __launch_bounds__(256) void trconv_kernel(
    const float* __restrict__ W, short* __restrict__ Wt, int K, int N) {
  __shared__ float ls[64][33];
  const int n0 = blockIdx.x * 32;
  const int k0 = blockIdx.y * 64;
  const int t = threadIdx.x;
#pragma unroll
  for (int it = 0; it < 2; ++it) {
    const int kr = (t >> 3) + it * 32;
    const int c4 = (t & 7) * 4;
    const float4 f = *(const float4*)&W[(size_t)(k0 + kr) * N + n0 + c4];
    ls[kr][c4] = f.x; ls[kr][c4 + 1] = f.y; ls[kr][c4 + 2] = f.z; ls[kr][c4 + 3] = f.w;
  }
  __syncthreads();
  const int r = t >> 3;           // 0..31 n-row
  const int kc = (t & 7) * 8;     // 0..56 k-chunk
  short8 s;
#pragma unroll
  for (int j = 0; j < 8; ++j) s[j] = f2bf(ls[kc + j][r]);
  *(short8*)&Wt[(size_t)(n0 + r) * K + k0 + kc] = s;
}

// -------- elementwise fp32 -> bf16 (8 per thread) ---------------------------
__global__ __launch_bounds__(256) void f2bf_kernel(
    const float* __restrict__ in, short* __restrict__ out) {
  const int i = blockIdx.x * 256 + threadIdx.x;
  const float4 a = *(const float4*)&in[(size_t)i * 8];
  const float4 b = *(const float4*)&in[(size_t)i * 8 + 4];
  short8 s;
  s[0] = f2bf(a.x); s[1] = f2bf(a.y); s[2] = f2bf(a.z); s[3] = f2bf(a.w);
  s[4] = f2bf(b.x); s[5] = f2bf(b.y); s[6] = f2bf(b.z); s[7] = f2bf(b.w);
  *(short8*)&out[(size_t)i * 8] = s;
}

// ---------- MFMA bf16 GEMM: C[M,N] (+)= A[M,K](bf16,lda) * Bt[N,K]^T --------
// Block tile 64m x 128n, BK=64 (16 MFMA per barrier-pair), 256 threads =
// 4 waves (2x2), wave = 32m x 64n. Register prefetch of next K-step during
// MFMA. Split-K via blockIdx.z (atom=1 -> atomicAdd into pre-zeroed C).
#define PAD2 72   // shorts per LDS row: 64 data + 8 pad (144 B, 16B-aligned)
__global__ __launch_bounds__(256) void gemm_bf16(
    const short* __restrict__ A, const short* __restrict__ Bt,
    float* __restrict__ C, int M, int N, int Kd, int lda, int klen, int atom) {
  __shared__ short As[64 * PAD2];    // 9216 B
  __shared__ short Bs[128 * PAD2];   // 18432 B
  const int tid = threadIdx.x;
  const int wave = tid >> 6, lane = tid & 63;
  const int wm = (wave >> 1) * 32, wn = (wave & 1) * 64;
  const int bm = blockIdx.y * 64, bn = blockIdx.x * 128;
  const int koff = blockIdx.z * klen;
  floatx4 acc[2][4] = {};
  const int sr = tid >> 3;            // 0..31 row base
  const int skc = (tid & 7) * 8;      // 0..56 k-chunk (8 shorts)
  const int fm = lane & 15, fq = (lane >> 4) * 8;
  const short* Ap = A  + koff + skc;
  const short* Bp = Bt + koff + skc;
  short8 pa[2], pb[4];
#pragma unroll
  for (int it = 0; it < 2; ++it)
    pa[it] = *(const short8*)(Ap + (size_t)(bm + sr + it * 32) * lda);
#pragma unroll
  for (int it = 0; it < 4; ++it)
    pb[it] = *(const short8*)(Bp + (size_t)(bn + sr + it * 32) * Kd);
  for (int k0 = 0; k0 < klen; k0 += 64) {
#pragma unroll
    for (int it = 0; it < 2; ++it)
      *(short8*)&As[(sr + it * 32) * PAD2 + skc] = pa[it];
#pragma unroll
    for (int it = 0; it < 4; ++it)
      *(short8*)&Bs[(sr + it * 32) * PAD2 + skc] = pb[it];
    __syncthreads();
    if (k0 + 64 < klen) {
#pragma unroll
      for (int it = 0; it < 2; ++it)
        pa[it] = *(const short8*)(Ap + (size_t)(bm + sr + it * 32) * lda + k0 + 64);
#pragma unroll
      for (int it = 0; it < 4; ++it)
        pb[it] = *(const short8*)(Bp + (size_t)(bn + sr + it * 32) * Kd + k0 + 64);
    }
    short8 af[2][2], bfr[2][4];
#pragma unroll
    for (int hh = 0; hh < 2; ++hh) {
#pragma unroll
      for (int i = 0; i < 2; ++i)
        af[hh][i] = *(const short8*)&As[(wm + i * 16 + fm) * PAD2 + hh * 32 + fq];
#pragma unroll
      for (int j = 0; j < 4; ++j)
        bfr[hh][j] = *(const short8*)&Bs[(wn + j * 16 + fm) * PAD2 + hh * 32 + fq];
    }
#pragma unroll
    for (int hh = 0; hh < 2; ++hh)
#pragma unroll
      for (int i = 0; i < 2; ++i)
#pragma unroll
        for (int j = 0; j < 4; ++j)
          acc[i][j] = __builtin_amdgcn_mfma_f32_16x16x32_bf16(af[hh][i], bfr[hh][j], acc[i][j], 0, 0, 0);
    __syncthreads();
  }
  const int cn = lane & 15, cr0 = (lane >> 4) * 4;
  if (atom) {
#pragma unroll
    for (int i = 0; i < 2; ++i)
#pragma unroll
      for (int j = 0; j < 4; ++j)
#pragma unroll
        for (int r = 0; r < 4; ++r)
          atomicAdd(&C[(size_t)(bm + wm + i * 16 + cr0 + r) * N + bn + wn + j * 16 + cn],
                    acc[i][j][r]);
  } else {
#pragma unroll
    for (int i = 0; i < 2; ++i)
#pragma unroll
      for (int j = 0; j < 4; ++j)
#pragma unroll
        for (int r = 0; r < 4; ++r)
          C[(size_t)(bm + wm + i * 16 + cr0 + r) * N + bn + wn + j * 16 + cn] = acc[i][j][r];
  }
}

// -------- b/a projections fused with gating --------
__global__ __launch_bounds__(256) void proj_ab_kernel(
    const float* __restrict__ hs, const float* __restrict__ Wb,
    const float* __restrict__ Wa, const float* __restrict__ A_log,
    const float* __restrict__ dt_bias, float* __restrict__ g_out,
    float* __restrict__ beta_out) {
  __shared__ float xs[HH];
  __shared__ float part[4][64];
  const int row = blockIdx.x;
  const int t = threadIdx.x;
  for (int i = t; i < HH; i += 256) xs[i] = hs[(size_t)row * HH + i];
  __syncthreads();
  const int j = t & 63;
  const int kc = t >> 6;
  const float* W = (j < 32) ? Wb : Wa;
  const int jj = j & 31;
  float p = 0.f;
  const int k0 = kc * 512;
#pragma unroll 8
  for (int k = k0; k < k0 + 512; ++k) p += xs[k] * W[k * 32 + jj];
  part[kc][j] = p;
  __syncthreads();
  if (t < 64) {
    float dot = part[0][t] + part[1][t] + part[2][t] + part[3][t];
    if (t < 32) {
      beta_out[row * HVc + t] = 1.f / (1.f + expf(-dot));
    } else {
      int h = t - 32;
      float x = dot + dt_bias[h];
      float sp = (x > 20.f) ? x : log1pf(expf(x));
      g_out[row * HVc + h] = -expf(A_log[h]) * sp;
    }
  }
}

// -------- depthwise causal conv (K=4) + SiLU, parallel over s-chunks --------
#define CCH 16
__global__ __launch_bounds__(256) void conv_par_kernel(
    const float* __restrict__ mixed, const float* __restrict__ conv_state,
    const float* __restrict__ conv_w, const float* __restrict__ conv_b,
    float* __restrict__ cs) {
  const int c = blockIdx.x * 256 + threadIdx.x;   // channel
  const int s0 = blockIdx.y * CCH;
  const int b = blockIdx.z;
  const float4 w4 = *(const float4*)&conv_w[c * KC];
  const float bias = conv_b[c];
  float r0, r1, r2;
  if (s0 == 0) {
    size_t sb = (size_t)(b * CONVD + c) * (KC - 1);
    r0 = conv_state[sb + 0]; r1 = conv_state[sb + 1]; r2 = conv_state[sb + 2];
  } else {
    r0 = mixed[((size_t)(b * SEQ + s0 - 3)) * CONVD + c];
    r1 = mixed[((size_t)(b * SEQ + s0 - 2)) * CONVD + c];
    r2 = mixed[((size_t)(b * SEQ + s0 - 1)) * CONVD + c];
  }
#pragma unroll
  for (int s = s0; s < s0 + CCH; ++s) {
    size_t off = ((size_t)(b * SEQ + s)) * CONVD + c;
    float x = mixed[off];
    float acc = bias + r0 * w4.x + r1 * w4.y + r2 * w4.z + x * w4.w;
    cs[off] = acc / (1.f + expf(-acc));
    r0 = r1; r1 = r2; r2 = x;
  }
}

// -------- conv_state_out: last K-1 raw rows of mixed, [B,C,K-1] fp32 --------
__global__ __launch_bounds__(256) void conv_state_out_kernel(
    const float* __restrict__ mixed, float* __restrict__ out2) {
  int idx = blockIdx.x * 256 + threadIdx.x;  // over BB*CONVD*(KC-1)
  int t = idx % (KC - 1);
  int c = (idx / (KC - 1)) & (CONVD - 1);
  int b = idx / ((KC - 1) * CONVD);
  out2[idx] = mixed[((size_t)(b * SEQ + SEQ - (KC - 1) + t)) * CONVD + c];
}

// -------- per-head l2norm of q (scaled by DK^-0.5) and k, IN PLACE on cs ----
__global__ __launch_bounds__(64) void l2norm_kernel(float* __restrict__ cs) {
  int bx = blockIdx.x;          // row*32 + head*2 + which
  int which = bx & 1;
  int head = (bx >> 1) & 15;
  int row = bx >> 5;
  int lane = threadIdx.x;
  size_t base = (size_t)row * CONVD + (size_t)which * KEYD + head * DKc;
  float v0 = cs[base + lane];
  float v1 = cs[base + lane + 64];
  float ss = v0 * v0 + v1 * v1;
#pragma unroll
  for (int m = 1; m < 64; m <<= 1) ss += __shfl_xor(ss, m, 64);
  float rn = rsqrtf(ss + EPSf);
  if (!which) rn *= 0.08838834764831845f;  // DK^-0.5
  cs[base + lane] = v0 * rn;
  cs[base + lane + 64] = v1 * rn;
}

// -------- delta-rule scan (v6, proven 163us): one wave/block, 2048 blocks ---
// Block = (vg 0..31, h, b): 4 v-cols per wave. lane = c4(0..3) + 4*kg(0..15).
// S[8] = state[kg*8 .. +8)[col]. Chunks of SCH=8 steps double-buffered in LDS;
// compact per-block-contiguous stores (no cross-XCD partial-line RMW).
// (v13 deferred-o variant regressed 164->207us with WRITE_SIZE 12->456MB —
// compiler-generated store amplification; reverted to the proven structure.)
#define SCH 8
__global__ __launch_bounds__(64, 2) void scan_kernel(
    const float* __restrict__ cs, const float* __restrict__ g_in,
    const float* __restrict__ beta_in, const float* __restrict__ rs0,
    const int* __restrict__ ctx, float* __restrict__ obuf,
    float* __restrict__ sftmp) {
  const int vg = blockIdx.x, h = blockIdx.y, b = blockIdx.z;
  const int bh = b * HVc + h;
  const int lane = threadIdx.x;
  const int kg = lane >> 2;         // k-sixteenth (0..15), owns 8 d-rows
  const int c4 = lane & 3;          // col within group
  const int col = vg * 4 + c4;
  const int khead = h >> 1;         // GQA rep=2
  __shared__ float kl[2][SCH * 128];
  __shared__ float ql[2][SCH * 128];
  __shared__ float vl[2][SCH * 4];
  __shared__ float egl[2][SCH];
  __shared__ float btl[2][SCH];
  float S[8];
#pragma unroll
  for (int i = 0; i < 8; ++i)
    S[i] = rs0[((size_t)bh * DKc + kg * 8 + i) * DVc + col];
  const int cl = ctx[b];
  const size_t qgo = (size_t)khead * DKc;
  const size_t kgo = KEYD + (size_t)khead * DKc;
  const size_t vG = 2 * KEYD + (size_t)h * DVc + vg * 4;
  const size_t obase = ((size_t)bh * 32 + vg) * (SEQ * 4);   // contiguous 4KB
  const int r0g = b * SEQ;
  const int kg8 = kg * 8;
  float4 kreg[4], qreg[4], vreg;
  float egr = 0.f, btr = 0.f;
  // ---- prologue: load + commit chunk 0
#pragma unroll
  for (int it = 0; it < 4; ++it) {
    int idx = it * 64 + lane, s = idx >> 5, d4 = idx & 31;
    const float* rp = cs + (size_t)(r0g + s) * CONVD;
    kreg[it] = *(const float4*)(rp + kgo + d4 * 4);
    qreg[it] = *(const float4*)(rp + qgo + d4 * 4);
  }
  if (lane < 8)       vreg = *(const float4*)(cs + (size_t)(r0g + lane) * CONVD + vG);
  else if (lane < 16) egr = expf(g_in[(r0g + lane - 8) * HVc + h]);
  else if (lane < 24) btr = beta_in[(r0g + lane - 16) * HVc + h];
#pragma unroll
  for (int it = 0; it < 4; ++it) {
    int idx = it * 64 + lane, s = idx >> 5, d4 = idx & 31;
    *(float4*)&kl[0][s * 128 + d4 * 4] = kreg[it];
    *(float4*)&ql[0][s * 128 + d4 * 4] = qreg[it];
  }
  if (lane < 8)       *(float4*)&vl[0][lane * 4] = vreg;
  else if (lane < 16) egl[0][lane - 8] = egr;
  else if (lane < 24) btl[0][lane - 16] = btr;

  const int NCH = SEQ / SCH;  // 32
  for (int c = 0; c < NCH; ++c) {
    const int buf = c & 1;
    // prefetch chunk c+1 into registers (hidden behind this chunk's compute)
    if (c + 1 < NCH) {
      const int r1 = r0g + (c + 1) * SCH;
#pragma unroll
      for (int it = 0; it < 4; ++it) {
        int idx = it * 64 + lane, s = idx >> 5, d4 = idx & 31;
        const float* rp = cs + (size_t)(r1 + s) * CONVD;
        kreg[it] = *(const float4*)(rp + kgo + d4 * 4);
        qreg[it] = *(const float4*)(rp + qgo + d4 * 4);
      }
      if (lane < 8)       vreg = *(const float4*)(cs + (size_t)(r1 + lane) * CONVD + vG);
      else if (lane < 16) egr = expf(g_in[(r1 + lane - 8) * HVc + h]);
      else if (lane < 24) btr = beta_in[(r1 + lane - 16) * HVc + h];
    }
    // compute SCH steps from LDS
#pragma unroll
    for (int s = 0; s < SCH; ++s) {
      const int sg = c * SCH + s;
      const float eg = egl[buf][s], bt = btl[buf][s];
      const float vv = vl[buf][s * 4 + c4];
      const float4* k4 = (const float4*)&kl[buf][s * 128 + kg8];
      const float4* q4 = (const float4*)&ql[buf][s * 128 + kg8];
      if (sg < cl) {
        const float4 kk0 = k4[0], kk1 = k4[1];
        float a0, a1, a2, a3;
        S[0] *= eg; a0 = kk0.x * S[0];
        S[1] *= eg; a1 = kk0.y * S[1];
        S[2] *= eg; a2 = kk0.z * S[2];
        S[3] *= eg; a3 = kk0.w * S[3];
        S[4] *= eg; a0 += kk1.x * S[4];
        S[5] *= eg; a1 += kk1.y * S[5];
        S[6] *= eg; a2 += kk1.z * S[6];
        S[7] *= eg; a3 += kk1.w * S[7];
        float p = (a0 + a1) + (a2 + a3);
        p += __shfl_xor(p, 4, 64);
        p += __shfl_xor(p, 8, 64);
        p += __shfl_xor(p, 16, 64);
        p += __shfl_xor(p, 32, 64);
        const float delta = (vv - p) * bt;
        const float4 qq0 = q4[0], qq1 = q4[1];
        float o0, o1, o2, o3;
        S[0] += kk0.x * delta; o0 = qq0.x * S[0];
        S[1] += kk0.y * delta; o1 = qq0.y * S[1];
        S[2] += kk0.z * delta; o2 = qq0.z * S[2];
        S[3] += kk0.w * delta; o3 = qq0.w * S[3];
        S[4] += kk1.x * delta; o0 += qq1.x * S[4];
        S[5] += kk1.y * delta; o1 += qq1.y * S[5];
        S[6] += kk1.z * delta; o2 += qq1.z * S[6];
        S[7] += kk1.w * delta; o3 += qq1.w * S[7];
        float o = (o0 + o1) + (o2 + o3);
        o += __shfl_xor(o, 4, 64);
        o += __shfl_xor(o, 8, 64);
        o += __shfl_xor(o, 16, 64);
        o += __shfl_xor(o, 32, 64);
        if (kg == 0) obuf[obase + sg * 4 + c4] = o;
      } else {
        if (kg == 0) obuf[obase + sg * 4 + c4] = 0.f;
      }
    }
    // commit prefetched chunk to the other LDS buffer
    if (c + 1 < NCH) {
      const int nb = buf ^ 1;
#pragma unroll
      for (int it = 0; it < 4; ++it) {
        int idx = it * 64 + lane, s = idx >> 5, d4 = idx & 31;
        *(float4*)&kl[nb][s * 128 + d4 * 4] = kreg[it];
        *(float4*)&ql[nb][s * 128 + d4 * 4] = qreg[it];
      }
      if (lane < 8)       *(float4*)&vl[nb][lane * 4] = vreg;
      else if (lane < 16) egl[nb][lane - 8] = egr;
      else if (lane < 24) btl[nb][lane - 16] = btr;
    }
  }
  // final state to compact per-block-contiguous buffer [bh][vg][dk][c4]
  const size_t sb = (((size_t)bh * 32 + vg) * DKc + kg8) * 4 + c4;
#pragma unroll
  for (int i = 0; i < 8; ++i)
    sftmp[sb + i * 4] = S[i];
}

// -------- sfin transpose: compact [bh][vg][dk][c4] -> out [bh][dk][dv] ------
__global__ __launch_bounds__(128) void sfin_tr_kernel(
    const float* __restrict__ sftmp, float* __restrict__ out_sf) {
  const int dk = blockIdx.x;
  const int bh = blockIdx.y;
  const int dv = threadIdx.x;
  out_sf[((size_t)bh * DKc + dk) * DVc + dv] =
      sftmp[(((size_t)bh * 32 + (dv >> 2)) * DKc + dk) * 4 + (dv & 3)];
}

// -------- gated RMSNorm over DV + SiLU(z): obuf -> bf16 A-matrix of GEMM3 ---
__global__ __launch_bounds__(64) void normgate_kernel(
    const float* __restrict__ obuf, const float* __restrict__ zbuf,
    const float* __restrict__ norm_w, short* __restrict__ o16) {
  int bx = blockIdx.x;   // row*32 + h
  int h = bx & 31;
  int row = bx >> 5;
  int b = row >> 8;      // row / SEQ
  int s = row & (SEQ - 1);
  int lane = threadIdx.x;
  size_t ob = ((size_t)(b * HVc + h) * 32 + (lane >> 2)) * (SEQ * 4) + s * 4 + (lane & 3);
  size_t zb = (size_t)row * VALD + h * DVc;
  float o0 = obuf[ob];
  float o1 = obuf[ob + 16 * (SEQ * 4)];
  float ss = o0 * o0 + o1 * o1;
#pragma unroll
  for (int m = 1; m < 64; m <<= 1) ss += __shfl_xor(ss, m, 64);
  float rms = rsqrtf(ss * (1.f / 128.f) + EPSf);
  float z0 = zbuf[zb + lane];
  float z1 = zbuf[zb + lane + 64];
  o16[zb + lane]      = f2bf(o0 * rms * norm_w[lane]      * (z0 / (1.f + expf(-z0))));
  o16[zb + lane + 64] = f2bf(o1 * rms * norm_w[lane + 64] * (z1 / (1.f + expf(-z1))));
}

extern "C" void kernel_launch(void* const* d_in, const int* in_sizes, int n_in,
                              void* d_out, int out_size, void* d_ws, size_t ws_size,
                              hipStream_t stream) {
  const float* hs        = (const float*)d_in[0];
  const float* conv_st   = (const float*)d_in[1];
  const float* rec_st    = (const float*)d_in[2];
  const int*   ctx       = (const int*)d_in[3];
  const float* W_qkv     = (const float*)d_in[4];
  const float* W_z       = (const float*)d_in[5];
  const float* W_b       = (const float*)d_in[6];
  const float* W_a       = (const float*)d_in[7];
  const float* conv_w    = (const float*)d_in[8];
  const float* conv_b    = (const float*)d_in[9];
  const float* A_log     = (const float*)d_in[10];
  const float* dt_bias   = (const float*)d_in[11];
  const float* norm_w    = (const float*)d_in[12];
  const float* W_out     = (const float*)d_in[13];

  float* out0   = (float*)d_out;                          // [B,S,H]
  float* out_cv = out0 + (size_t)MM * HH;                 // [B,CONVD,K-1]
  float* out_sf = out_cv + (size_t)BB * CONVD * (KC - 1); // [B,HV,DK,DV]

  // Workspace layout (time-aliased; ~54 MB):
  //  [0,16M)   mixed (fp32 GEMM1 out; later obuf 8M + sftmp 4M)
  //  [16M,48M) wt: weight transpose region (Wqkv_t 32M / Wz_t 16M / Wout_t 16M)
  //            cs aliases [16M,32M); zbuf at [32M,40M)
  //  [48M,..)  gbuf, betab, hs16 (2M), o16 (4M)
  char*  base  = (char*)d_ws;
  float* mixed = (float*)base;
  char*  wtB   = base + (size_t)MM * CONVD * 4;
  short* wt    = (short*)wtB;
  float* cs    = (float*)wtB;
  float* zbuf  = (float*)(wtB + (size_t)MM * CONVD * 4);
  float* gbuf  = (float*)(wtB + (size_t)CONVD * HH * 2);
  float* betab = gbuf + (size_t)MM * HVc;
  short* hs16  = (short*)(betab + (size_t)MM * HVc);
  short* o16   = hs16 + (size_t)MM * HH;
  float* obuf  = mixed;
  float* sftmp = mixed + (size_t)MM * VALD;

  // 0a) hs -> bf16
  f2bf_kernel<<<(MM * HH / 8) / 256, 256, 0, stream>>>(hs, hs16);
  // 0b) W_qkv -> Wqkv_t [CONVD][HH] bf16
  trconv_kernel<<<dim3(CONVD / 32, HH / 64), 256, 0, stream>>>(W_qkv, wt, HH, CONVD);
  // 1) mixed = hs16 @ Wqkv_t^T, split-K x2 (atomic; zero first)
  zerof_kernel<<<(MM * CONVD / 4) / 256, 256, 0, stream>>>(mixed);
  gemm_bf16<<<dim3(CONVD / 128, MM / 64, 2), 256, 0, stream>>>(
      hs16, wt, mixed, MM, CONVD, HH, HH, HH / 2, 1);
  // 2a) W_z -> Wz_t [VALD][HH] bf16 (Wqkv_t dead)
  trconv_kernel<<<dim3(VALD / 32, HH / 64), 256, 0, stream>>>(W_z, wt, HH, VALD);
  // 2b) z = hs16 @ Wz_t^T, split-K x2
  zerof_kernel<<<(MM * VALD / 4) / 256, 256, 0, stream>>>(zbuf);
  gemm_bf16<<<dim3(VALD / 128, MM / 64, 2), 256, 0, stream>>>(
      hs16, wt, zbuf, MM, VALD, HH, HH, HH / 2, 1);
  // 3) b,a projections + gating
  proj_ab_kernel<<<MM, 256, 0, stream>>>(hs, W_b, W_a, A_log, dt_bias, gbuf, betab);
  // 4) conv + silu (mixed -> cs; overwrites dead Wz_t)
  conv_par_kernel<<<dim3(CONVD / 256, SEQ / CCH, BB), 256, 0, stream>>>(
      mixed, conv_st, conv_w, conv_b, cs);
  // 5) conv_state_out from raw mixed
  conv_state_out_kernel<<<(BB * CONVD * (KC - 1)) / 256, 256, 0, stream>>>(mixed, out_cv);
  // 6) l2norm q,k in place on cs
  l2norm_kernel<<<MM * HKc * 2, 64, 0, stream>>>(cs);
  // 7) delta-rule scan (v6 chunked-LDS, proven): compact contiguous stores
  scan_kernel<<<dim3(32, HVc, BB), 64, 0, stream>>>(cs, gbuf, betab, rec_st, ctx, obuf, sftmp);
  // 7b) transpose compact Sfin -> out_sf [B,HV,DK,DV]
  sfin_tr_kernel<<<dim3(DKc, BB * HVc), 128, 0, stream>>>(sftmp, out_sf);
  // 8) gated RMSNorm + silu(z): obuf,zbuf -> o16 (bf16 A of GEMM3)
  normgate_kernel<<<MM * HVc, 64, 0, stream>>>(obuf, zbuf, norm_w, o16);
  // 9a) W_out -> Wout_t [HH][VALD] bf16 (overwrites dead cs)
  trconv_kernel<<<dim3(HH / 32, VALD / 64), 256, 0, stream>>>(W_out, wt, VALD, HH);
  // 9b) output = o16 @ Wout_t^T, split-K x4
  zerof_kernel<<<(MM * HH / 4) / 256, 256, 0, stream>>>(out0);
  gemm_bf16<<<dim3(HH / 128, MM / 64, 4), 256, 0, stream>>>(
      o16, wt, out0, MM, HH, VALD, VALD, VALD / 4, 1);
}